// Round 21
// baseline (121.447 us; speedup 1.0000x reference)
//
#include <hip/hip_runtime.h>

#define B_ 8
#define T_ 256
#define U_ 64
#define U1_ 65
#define V_ 512
#define NDIAGP_ 336
#define NT_ 2                      // t-rows per producer block
#define NPROD_ (B_ * T_ / NT_)     // 1024 producer blocks
#define NTG_ (T_ / NT_)            // 128 flags per batch
#define CH_ 64                     // diagonals per chunk
#define MAGIC_ 0x5F3C9D71

#define LOG2E_ 1.4426950408889634f
#define LN2_   0.6931471805599453f

#if __has_builtin(__builtin_amdgcn_exp2f)
#define EXP2(x) __builtin_amdgcn_exp2f(x)
#else
#define EXP2(x) exp2f(x)
#endif

// ---------------------------------------------------------------------------
// DPP helpers
// ---------------------------------------------------------------------------
template <int CTRL, int RM>
__device__ __forceinline__ float dppadd(float x) {
    return x + __int_as_float(__builtin_amdgcn_update_dpp(
        0, __float_as_int(x), CTRL, RM, 0xf, true));
}
__device__ __forceinline__ float wave_sum64(float x) {
    x = dppadd<0x111, 0xf>(x);
    x = dppadd<0x112, 0xf>(x);
    x = dppadd<0x114, 0xf>(x);
    x = dppadd<0x118, 0xf>(x);
    x = dppadd<0x142, 0xa>(x);
    x = dppadd<0x143, 0xc>(x);
    return x;                    // lane 63 holds the full sum
}
__device__ __forceinline__ float wshr1(float x) {
    return __int_as_float(__builtin_amdgcn_update_dpp(
        0, __float_as_int(x), 0x138, 0xf, 0xf, true));
}
template <int CTRL>
__device__ __forceinline__ float dppmax(float x) {
    return fmaxf(x, __int_as_float(__builtin_amdgcn_update_dpp(
        0, __float_as_int(x), CTRL, 0xf, 0xf, false)));
}
__device__ __forceinline__ float wave_max64(float x) {
    x = dppmax<0x111>(x);
    x = dppmax<0x112>(x);
    x = dppmax<0x114>(x);
    x = dppmax<0x118>(x);
    x = dppmax<0x142>(x);
    x = dppmax<0x143>(x);
    return __int_as_float(__builtin_amdgcn_readlane(__float_as_int(x), 63));
}

// Spin until flags[0..lim] all MAGIC (each lane watches 2 flags; acquire).
__device__ __forceinline__ void wait2(const int* fb, int lim, int lane) {
    const int i0 = (2 * lane     < lim) ? 2 * lane     : lim;
    const int i1 = (2 * lane + 1 < lim) ? 2 * lane + 1 : lim;
    for (;;) {
        int v0 = __hip_atomic_load(fb + i0, __ATOMIC_ACQUIRE,
                                   __HIP_MEMORY_SCOPE_AGENT);
        int v1 = __hip_atomic_load(fb + i1, __ATOMIC_ACQUIRE,
                                   __HIP_MEMORY_SCOPE_AGENT);
        if (__all(v0 == MAGIC_ && v1 == MAGIC_)) return;
        __builtin_amdgcn_s_sleep(8);
    }
}

// ---------------------------------------------------------------------------
// Consumer chunk conversion: waves 1-3 convert rows [64c, 64c+64) from
// GLOBAL BLD/EMD into bf16-packed PV (+pc) LDS buffer (c&1). Reg-batched 8.
// Row semantics: refcol = row<256 ? 0 : row-255; t==0 patch row<64&&lane==row;
// dead lanes row>=256 && lane <= row-256. (R20-proven forms.)
// ---------------------------------------------------------------------------
#define CONVC(c_) do {                                                          \
    const int d0_ = CH_ * (c_);                                                 \
    for (int k0 = 0; k0 < 24; k0 += 8) {                                        \
        float bl[8], em[8], pcv[8];                                             \
        int   rix[8];                                                           \
        _Pragma("unroll")                                                       \
        for (int j = 0; j < 8; ++j) {                                           \
            int i = (wave - 1) + 3 * (k0 + j);                                  \
            rix[j] = (i < CH_) ? i : -1;                                        \
            const int row = d0_ + ((i < CH_) ? i : CH_ - 1);                    \
            const int rc  = row < 256 ? 0 : row - 255;                          \
            bl[j]  = BLb[(size_t)row * U1_ + lane + 1];                         \
            em[j]  = EMb[(size_t)row * U_ + lane];                              \
            pcv[j] = BLb[(size_t)row * U1_ + rc];                               \
        }                                                                       \
        _Pragma("unroll")                                                       \
        for (int j = 0; j < 8; ++j) {                                           \
            if (rix[j] < 0) continue;                                           \
            const int i = rix[j];                                               \
            const int row = d0_ + i;                                            \
            float vb = fminf(bl[j] - pcv[j], 126.0f);                           \
            float ve = fminf(em[j] - pcv[j], 126.0f);                           \
            if (row < 64 && lane == row) vb = -200.0f;                          \
            if (row >= 256 && lane <= row - 256) { vb = -200.0f; ve = -200.0f; }\
            const unsigned int ub = __float_as_uint(EXP2(vb)) + 0x8000u;        \
            const unsigned int ue = __float_as_uint(EXP2(ve)) + 0x8000u;        \
            sPV[(c_) & 1][i * 64 + lane] = (ub & 0xffff0000u) | (ue >> 16);     \
            if (lane == 0) sPC[(c_) & 1][i] = pcv[j];                           \
        }                                                                       \
    }                                                                           \
} while (0)

#define LOADG(PW, PCQ, g_) do {                                                 \
    _Pragma("unroll")                                                           \
    for (int j = 0; j < 8; ++j)                                                 \
        PW[j] = pvb[(8 * (g_) + j) * 64 + lane];                                \
    PCQ[0] = pc4[2 * (g_)];                                                     \
    PCQ[1] = pc4[2 * (g_) + 1];                                                 \
} while (0)

#define PCSEL(PCQ, j_) ((j_) < 4 ? ((j_) == 0 ? PCQ[0].x : (j_) == 1 ? PCQ[0].y \
                                  : (j_) == 2 ? PCQ[0].z : PCQ[0].w)            \
                                 : ((j_) == 4 ? PCQ[1].x : (j_) == 5 ? PCQ[1].y \
                                  : (j_) == 6 ? PCQ[1].z : PCQ[1].w))

#define COMPG(PW, PCQ, g_) do {                                                 \
    _Pragma("unroll")                                                           \
    for (int j = 0; j < 8; ++j) {                                               \
        const int d = d0 + 8 * (g_) + j + 1;                                    \
        const unsigned int w = PW[j];                                           \
        const float pbv = __uint_as_float(w & 0xffff0000u);                     \
        const float pev = __uint_as_float(w << 16);                             \
        const float pcj = PCSEL(PCQ, j);                                        \
        float sr = wshr1(r);                                                    \
        sr = lane0 ? r0 : sr;                                                   \
        r = fmaf(sr, pev, r * pbv);                                             \
        const bool cap = (d == cap_d);                                          \
        savedV = cap ? (tlpos ? r : r0) : savedV;                               \
        savedC = cap ? (tlpos ? Rc + pcj : Rc) : savedC;                        \
        Rc += pcj;                                                              \
    }                                                                           \
    {   /* renorm by exact 2^-e (branchless) */                                 \
        float m = wave_max64(r);                                                \
        int mb = __float_as_int(m);                                             \
        int e = (mb >> 23) - 127;                                               \
        e = (mb >= 0x00800000) ? e : 0;                                         \
        float sc = __int_as_float((127 - e) << 23);                             \
        r *= sc;  r0 *= sc;  Rc += (float)e;                                    \
    }                                                                           \
} while (0)

#define CHUNK_BODY(c_) do {                                                     \
    const unsigned int* pvb = sPV[(c_) & 1];                                    \
    const float4* pc4 = (const float4*)sPC[(c_) & 1];                           \
    const int d0 = CH_ * (c_);                                                  \
    unsigned int pwA[8], pwB[8];                                                \
    float4 pcA[2], pcB[2];                                                      \
    LOADG(pwA, pcA, 0);                                                         \
    for (int g = 0; g < 8; g += 2) {                                            \
        LOADG(pwB, pcB, g + 1);                                                 \
        COMPG(pwA, pcA, g);                                                     \
        if (g + 2 < 8) LOADG(pwA, pcA, g + 2);                                  \
        COMPG(pwB, pcB, g + 1);                                                 \
    }                                                                           \
} while (0)

// ---------------------------------------------------------------------------
// Fused kernel: blocks 0..1023 = producers (R18 k_logprobs + release flag);
// blocks 1024..1031 = consumers (flag-waited chunked alpha recursion).
// LDS = 33.3 KB -> 4 blocks/CU: all producers co-resident (R19's bug fixed).
// ---------------------------------------------------------------------------
__global__ __launch_bounds__(256) void k_fused(
    const float* __restrict__ enc, const float* __restrict__ dec,
    const int* __restrict__ targets,
    const int* __restrict__ il_, const int* __restrict__ tl_,
    float* __restrict__ BLD, float* __restrict__ EMD,
    int* __restrict__ flags, float* __restrict__ partial,
    int* __restrict__ pflag, float* __restrict__ out)
{
    __shared__ __align__(16) unsigned int sPV[2][CH_ * 64];  // 32 KB
    __shared__ __align__(16) float        sPC[2][CH_];       // 512 B

    const int blk  = blockIdx.x;
    const int wave = threadIdx.x >> 6;
    const int lane = threadIdx.x & 63;

    if (blk < NPROD_) {
        // ========================= producer =========================
        const int b  = blk % B_;
        const int tg = blk / B_;
        const int t0 = tg * NT_;

        float4 xe0[NT_], xe1[NT_];
        float  er0[NT_];
        #pragma unroll
        for (int j = 0; j < NT_; ++j) {
            const float* erow = enc + (size_t)(b * T_ + t0 + j) * V_;
            float4 e0 = *(const float4*)(erow + lane * 4);
            float4 e1 = *(const float4*)(erow + 256 + lane * 4);
            xe0[j].x = __expf(e0.x); xe0[j].y = __expf(e0.y);
            xe0[j].z = __expf(e0.z); xe0[j].w = __expf(e0.w);
            xe1[j].x = __expf(e1.x); xe1[j].y = __expf(e1.y);
            xe1[j].z = __expf(e1.z); xe1[j].w = __expf(e1.w);
            er0[j] = erow[0];
        }

        for (int u = wave; u <= U_; u += 4) {
            const float* drow = dec + (size_t)(b * U1_ + u) * V_;
            float4 d0 = *(const float4*)(drow + lane * 4);
            float4 d1 = *(const float4*)(drow + 256 + lane * 4);
            d0.x = __expf(d0.x); d0.y = __expf(d0.y);
            d0.z = __expf(d0.z); d0.w = __expf(d0.w);
            d1.x = __expf(d1.x); d1.y = __expf(d1.y);
            d1.z = __expf(d1.z); d1.w = __expf(d1.w);

            float s[NT_];
            #pragma unroll
            for (int j = 0; j < NT_; ++j) {
                float sA = xe0[j].x * d0.x;
                float sB = xe1[j].x * d1.x;
                sA = fmaf(xe0[j].y, d0.y, sA);  sB = fmaf(xe1[j].y, d1.y, sB);
                sA = fmaf(xe0[j].z, d0.z, sA);  sB = fmaf(xe1[j].z, d1.z, sB);
                sA = fmaf(xe0[j].w, d0.w, sA);  sB = fmaf(xe1[j].w, d1.w, sB);
                s[j] = sA + sB;
            }

            #pragma unroll
            for (int j = 0; j < NT_; ++j)
                s[j] = wave_sum64(s[j]);

            if (lane == 63) {
                const float d_blank = drow[0];
                int   tgt = 0;
                float d_tgt = 0.0f;
                if (u < U_) { tgt = targets[b * U_ + u]; d_tgt = drow[tgt]; }
                #pragma unroll
                for (int j = 0; j < NT_; ++j) {
                    const int t  = t0 + j;
                    const int dg = t + u;
                    const float lse2 = log2f(s[j]);
                    BLD[((size_t)b * NDIAGP_ + dg) * U1_ + u] =
                        (er0[j] + d_blank) * LOG2E_ - lse2;
                    if (u < U_) {
                        const float* er = enc + (size_t)(b * T_ + t) * V_;
                        EMD[((size_t)b * NDIAGP_ + dg) * U_ + u] =
                            (er[tgt] + d_tgt) * LOG2E_ - lse2;
                    }
                }
            }
        }
        __syncthreads();
        __threadfence();
        if (threadIdx.x == 0)
            __hip_atomic_store(&flags[b * NTG_ + tg], MAGIC_,
                               __ATOMIC_RELEASE, __HIP_MEMORY_SCOPE_AGENT);
        return;
    }

    // ========================= consumer =========================
    const int b = blk - NPROD_;
    const int* fb = flags + b * NTG_;
    const int il   = il_[b];
    const int tl   = tl_[b];
    const int dstar = il - 1 + tl;
    const float* BLb = BLD + (size_t)b * NDIAGP_ * U1_;
    const float* EMb = EMD + (size_t)b * NDIAGP_ * U_;

    const bool lane0 = (lane == 0);
    const bool tlpos = (tl > 0);
    const int  cap_d = tlpos ? dstar : il;

    float r  = 0.0f;
    float r0 = 1.0f;
    float Rc = 0.0f;
    float savedV = 1.0f, savedC = 0.0f;

    // chunk c needs producer groups tg <= 32c+31
    if (wave > 0) { wait2(fb, 31, lane); CONVC(0); }
    __syncthreads();

    for (int c = 0; c < 5; ++c) {
        if (wave > 0 && c + 1 <= 4) {
            const int lim = 32 * (c + 1) + 31;
            wait2(fb, lim > NTG_ - 1 ? NTG_ - 1 : lim, lane);
            CONVC(c + 1);
        }
        if (wave == 0) { CHUNK_BODY(c); }
        __syncthreads();
    }

    if (wave == 0) {
        wait2(fb, NTG_ - 1, lane);   // all flags set (instant); acquire for fblank
        const float fblank = BLb[(size_t)dstar * U1_ + tl];
        const int sl = tlpos ? (tl - 1) : 0;
        float sv = __int_as_float(
            __builtin_amdgcn_readlane(__float_as_int(savedV), sl));
        float sc = __int_as_float(
            __builtin_amdgcn_readlane(__float_as_int(savedC), 0));
        if (lane == 0) {
            const float term = sc + log2f(sv) + fblank;
            if (b == 0) {
                float sum = term;
                for (int l = 1; l < B_; ++l) {
                    while (__hip_atomic_load(&pflag[l], __ATOMIC_ACQUIRE,
                                             __HIP_MEMORY_SCOPE_AGENT) != MAGIC_)
                        __builtin_amdgcn_s_sleep(8);
                    sum += partial[l];
                }
                out[0] = -sum * (LN2_ / B_);
            } else {
                partial[b] = term;
                __threadfence();
                __hip_atomic_store(&pflag[b], MAGIC_,
                                   __ATOMIC_RELEASE, __HIP_MEMORY_SCOPE_AGENT);
            }
        }
    }
}

extern "C" void kernel_launch(void* const* d_in, const int* in_sizes, int n_in,
                              void* d_out, int out_size, void* d_ws, size_t ws_size,
                              hipStream_t stream)
{
    const float* enc     = (const float*)d_in[0];
    const float* dec     = (const float*)d_in[1];
    const int*   targets = (const int*)d_in[2];
    const int*   il      = (const int*)d_in[3];
    const int*   tl      = (const int*)d_in[4];
    float*       out     = (float*)d_out;

    float* BLD     = (float*)d_ws;                              // B*NDIAGP*U1
    float* EMD     = BLD + (size_t)B_ * NDIAGP_ * U1_;          // B*NDIAGP*U_
    int*   flags   = (int*)(EMD + (size_t)B_ * NDIAGP_ * U_);   // B*NTG_
    float* partial = (float*)(flags + B_ * NTG_);               // B_ floats
    int*   pflag   = (int*)(partial + B_);                      // B_ ints

    k_fused<<<NPROD_ + B_, 256, 0, stream>>>(enc, dec, targets, il, tl,
                                             BLD, EMD, flags, partial, pflag, out);
}

// Round 22
// 121.117 us; speedup vs baseline: 1.0027x; 1.0027x over previous
//
#include <hip/hip_runtime.h>

#define B_ 8
#define T_ 256
#define U_ 64
#define U1_ 65
#define V_ 512
#define NDIAGP_ 336
#define NT_ 2                      // t-rows per producer block
#define NPROD_ (B_ * T_ / NT_)     // 1024 producer blocks
#define NTG_ (T_ / NT_)            // 128 flags per batch
#define CH_ 64                     // diagonals per chunk
#define MAGIC_ 0x5F3C9D71

#define LOG2E_ 1.4426950408889634f
#define LN2_   0.6931471805599453f

#if __has_builtin(__builtin_amdgcn_exp2f)
#define EXP2(x) __builtin_amdgcn_exp2f(x)
#else
#define EXP2(x) exp2f(x)
#endif

// ---------------------------------------------------------------------------
// DPP helpers
// ---------------------------------------------------------------------------
template <int CTRL, int RM>
__device__ __forceinline__ float dppadd(float x) {
    return x + __int_as_float(__builtin_amdgcn_update_dpp(
        0, __float_as_int(x), CTRL, RM, 0xf, true));
}
__device__ __forceinline__ float wave_sum64(float x) {
    x = dppadd<0x111, 0xf>(x);
    x = dppadd<0x112, 0xf>(x);
    x = dppadd<0x114, 0xf>(x);
    x = dppadd<0x118, 0xf>(x);
    x = dppadd<0x142, 0xa>(x);
    x = dppadd<0x143, 0xc>(x);
    return x;                    // lane 63 holds the full sum
}
__device__ __forceinline__ float wshr1(float x) {
    return __int_as_float(__builtin_amdgcn_update_dpp(
        0, __float_as_int(x), 0x138, 0xf, 0xf, true));
}
template <int CTRL>
__device__ __forceinline__ float dppmax(float x) {
    return fmaxf(x, __int_as_float(__builtin_amdgcn_update_dpp(
        0, __float_as_int(x), CTRL, 0xf, 0xf, false)));
}
__device__ __forceinline__ float wave_max64(float x) {
    x = dppmax<0x111>(x);
    x = dppmax<0x112>(x);
    x = dppmax<0x114>(x);
    x = dppmax<0x118>(x);
    x = dppmax<0x142>(x);
    x = dppmax<0x143>(x);
    return __int_as_float(__builtin_amdgcn_readlane(__float_as_int(x), 63));
}

// Spin until flags[0..lim] all MAGIC (each lane watches 2 flags; acquire).
__device__ __forceinline__ void wait2(const int* fb, int lim, int lane) {
    const int i0 = (2 * lane     < lim) ? 2 * lane     : lim;
    const int i1 = (2 * lane + 1 < lim) ? 2 * lane + 1 : lim;
    for (;;) {
        int v0 = __hip_atomic_load(fb + i0, __ATOMIC_ACQUIRE,
                                   __HIP_MEMORY_SCOPE_AGENT);
        int v1 = __hip_atomic_load(fb + i1, __ATOMIC_ACQUIRE,
                                   __HIP_MEMORY_SCOPE_AGENT);
        if (__all(v0 == MAGIC_ && v1 == MAGIC_)) return;
        __builtin_amdgcn_s_sleep(8);
    }
}

// ---------------------------------------------------------------------------
// Consumer chunk conversion: waves 1-3 convert rows [64c, 64c+64) from
// GLOBAL BLD/EMD into bf16-packed PV (+pc) LDS buffer (c&1). Reg-batched 8.
// Row semantics: refcol = row<256 ? 0 : row-255; t==0 patch row<64&&lane==row;
// dead lanes row>=256 && lane <= row-256. (R20-proven forms.)
// ---------------------------------------------------------------------------
#define CONVC(c_) do {                                                          \
    const int d0_ = CH_ * (c_);                                                 \
    for (int k0 = 0; k0 < 24; k0 += 8) {                                        \
        float bl[8], em[8], pcv[8];                                             \
        int   rix[8];                                                           \
        _Pragma("unroll")                                                       \
        for (int j = 0; j < 8; ++j) {                                           \
            int i = (wave - 1) + 3 * (k0 + j);                                  \
            rix[j] = (i < CH_) ? i : -1;                                        \
            const int row = d0_ + ((i < CH_) ? i : CH_ - 1);                    \
            const int rc  = row < 256 ? 0 : row - 255;                          \
            bl[j]  = BLb[(size_t)row * U1_ + lane + 1];                         \
            em[j]  = EMb[(size_t)row * U_ + lane];                              \
            pcv[j] = BLb[(size_t)row * U1_ + rc];                               \
        }                                                                       \
        _Pragma("unroll")                                                       \
        for (int j = 0; j < 8; ++j) {                                           \
            if (rix[j] < 0) continue;                                           \
            const int i = rix[j];                                               \
            const int row = d0_ + i;                                            \
            float vb = fminf(bl[j] - pcv[j], 126.0f);                           \
            float ve = fminf(em[j] - pcv[j], 126.0f);                           \
            if (row < 64 && lane == row) vb = -200.0f;                          \
            if (row >= 256 && lane <= row - 256) { vb = -200.0f; ve = -200.0f; }\
            const unsigned int ub = __float_as_uint(EXP2(vb)) + 0x8000u;        \
            const unsigned int ue = __float_as_uint(EXP2(ve)) + 0x8000u;        \
            sPV[(c_) & 1][i * 64 + lane] = (ub & 0xffff0000u) | (ue >> 16);     \
            if (lane == 0) sPC[(c_) & 1][i] = pcv[j];                           \
        }                                                                       \
    }                                                                           \
} while (0)

#define LOADG(PW, PCQ, g_) do {                                                 \
    _Pragma("unroll")                                                           \
    for (int j = 0; j < 8; ++j)                                                 \
        PW[j] = pvb[(8 * (g_) + j) * 64 + lane];                                \
    PCQ[0] = pc4[2 * (g_)];                                                     \
    PCQ[1] = pc4[2 * (g_) + 1];                                                 \
} while (0)

#define PCSEL(PCQ, j_) ((j_) < 4 ? ((j_) == 0 ? PCQ[0].x : (j_) == 1 ? PCQ[0].y \
                                  : (j_) == 2 ? PCQ[0].z : PCQ[0].w)            \
                                 : ((j_) == 4 ? PCQ[1].x : (j_) == 5 ? PCQ[1].y \
                                  : (j_) == 6 ? PCQ[1].z : PCQ[1].w))

#define COMPG(PW, PCQ, g_) do {                                                 \
    _Pragma("unroll")                                                           \
    for (int j = 0; j < 8; ++j) {                                               \
        const int d = d0 + 8 * (g_) + j + 1;                                    \
        const unsigned int w = PW[j];                                           \
        const float pbv = __uint_as_float(w & 0xffff0000u);                     \
        const float pev = __uint_as_float(w << 16);                             \
        const float pcj = PCSEL(PCQ, j);                                        \
        float sr = wshr1(r);                                                    \
        sr = lane0 ? r0 : sr;                                                   \
        r = fmaf(sr, pev, r * pbv);                                             \
        const bool cap = (d == cap_d);                                          \
        savedV = cap ? (tlpos ? r : r0) : savedV;                               \
        savedC = cap ? (tlpos ? Rc + pcj : Rc) : savedC;                        \
        Rc += pcj;                                                              \
    }                                                                           \
    {   /* renorm by exact 2^-e (branchless) */                                 \
        float m = wave_max64(r);                                                \
        int mb = __float_as_int(m);                                             \
        int e = (mb >> 23) - 127;                                               \
        e = (mb >= 0x00800000) ? e : 0;                                         \
        float sc = __int_as_float((127 - e) << 23);                             \
        r *= sc;  r0 *= sc;  Rc += (float)e;                                    \
    }                                                                           \
} while (0)

#define CHUNK_BODY(c_) do {                                                     \
    const unsigned int* pvb = sPV[(c_) & 1];                                    \
    const float4* pc4 = (const float4*)sPC[(c_) & 1];                           \
    const int d0 = CH_ * (c_);                                                  \
    unsigned int pwA[8], pwB[8];                                                \
    float4 pcA[2], pcB[2];                                                      \
    LOADG(pwA, pcA, 0);                                                         \
    for (int g = 0; g < 8; g += 2) {                                            \
        LOADG(pwB, pcB, g + 1);                                                 \
        COMPG(pwA, pcA, g);                                                     \
        if (g + 2 < 8) LOADG(pwA, pcA, g + 2);                                  \
        COMPG(pwB, pcB, g + 1);                                                 \
    }                                                                           \
} while (0)

// ---------------------------------------------------------------------------
// Fused kernel: blocks 0..1023 = producers (R18 k_logprobs + release flag);
// blocks 1024..1031 = consumers (flag-waited chunked alpha recursion).
// LDS = 33.3 KB -> 4 blocks/CU: all producers co-resident (R19's bug fixed).
// ---------------------------------------------------------------------------
__global__ __launch_bounds__(256) void k_fused(
    const float* __restrict__ enc, const float* __restrict__ dec,
    const int* __restrict__ targets,
    const int* __restrict__ il_, const int* __restrict__ tl_,
    float* __restrict__ BLD, float* __restrict__ EMD,
    int* __restrict__ flags, float* __restrict__ partial,
    int* __restrict__ pflag, float* __restrict__ out)
{
    __shared__ __align__(16) unsigned int sPV[2][CH_ * 64];  // 32 KB
    __shared__ __align__(16) float        sPC[2][CH_];       // 512 B

    const int blk  = blockIdx.x;
    const int wave = threadIdx.x >> 6;
    const int lane = threadIdx.x & 63;

    if (blk < NPROD_) {
        // ========================= producer =========================
        const int b  = blk % B_;
        const int tg = blk / B_;
        const int t0 = tg * NT_;

        float4 xe0[NT_], xe1[NT_];
        float  er0[NT_];
        #pragma unroll
        for (int j = 0; j < NT_; ++j) {
            const float* erow = enc + (size_t)(b * T_ + t0 + j) * V_;
            float4 e0 = *(const float4*)(erow + lane * 4);
            float4 e1 = *(const float4*)(erow + 256 + lane * 4);
            xe0[j].x = __expf(e0.x); xe0[j].y = __expf(e0.y);
            xe0[j].z = __expf(e0.z); xe0[j].w = __expf(e0.w);
            xe1[j].x = __expf(e1.x); xe1[j].y = __expf(e1.y);
            xe1[j].z = __expf(e1.z); xe1[j].w = __expf(e1.w);
            er0[j] = erow[0];
        }

        for (int u = wave; u <= U_; u += 4) {
            const float* drow = dec + (size_t)(b * U1_ + u) * V_;
            float4 d0 = *(const float4*)(drow + lane * 4);
            float4 d1 = *(const float4*)(drow + 256 + lane * 4);
            d0.x = __expf(d0.x); d0.y = __expf(d0.y);
            d0.z = __expf(d0.z); d0.w = __expf(d0.w);
            d1.x = __expf(d1.x); d1.y = __expf(d1.y);
            d1.z = __expf(d1.z); d1.w = __expf(d1.w);

            float s[NT_];
            #pragma unroll
            for (int j = 0; j < NT_; ++j) {
                float sA = xe0[j].x * d0.x;
                float sB = xe1[j].x * d1.x;
                sA = fmaf(xe0[j].y, d0.y, sA);  sB = fmaf(xe1[j].y, d1.y, sB);
                sA = fmaf(xe0[j].z, d0.z, sA);  sB = fmaf(xe1[j].z, d1.z, sB);
                sA = fmaf(xe0[j].w, d0.w, sA);  sB = fmaf(xe1[j].w, d1.w, sB);
                s[j] = sA + sB;
            }

            #pragma unroll
            for (int j = 0; j < NT_; ++j)
                s[j] = wave_sum64(s[j]);

            if (lane == 63) {
                const float d_blank = drow[0];
                int   tgt = 0;
                float d_tgt = 0.0f;
                if (u < U_) { tgt = targets[b * U_ + u]; d_tgt = drow[tgt]; }
                #pragma unroll
                for (int j = 0; j < NT_; ++j) {
                    const int t  = t0 + j;
                    const int dg = t + u;
                    const float lse2 = log2f(s[j]);
                    BLD[((size_t)b * NDIAGP_ + dg) * U1_ + u] =
                        (er0[j] + d_blank) * LOG2E_ - lse2;
                    if (u < U_) {
                        const float* er = enc + (size_t)(b * T_ + t) * V_;
                        EMD[((size_t)b * NDIAGP_ + dg) * U_ + u] =
                            (er[tgt] + d_tgt) * LOG2E_ - lse2;
                    }
                }
            }
        }
        __syncthreads();
        __threadfence();
        if (threadIdx.x == 0)
            __hip_atomic_store(&flags[b * NTG_ + tg], MAGIC_,
                               __ATOMIC_RELEASE, __HIP_MEMORY_SCOPE_AGENT);
        return;
    }

    // ========================= consumer =========================
    const int b = blk - NPROD_;
    const int* fb = flags + b * NTG_;
    const int il   = il_[b];
    const int tl   = tl_[b];
    const int dstar = il - 1 + tl;
    const float* BLb = BLD + (size_t)b * NDIAGP_ * U1_;
    const float* EMb = EMD + (size_t)b * NDIAGP_ * U_;

    const bool lane0 = (lane == 0);
    const bool tlpos = (tl > 0);
    const int  cap_d = tlpos ? dstar : il;

    float r  = 0.0f;
    float r0 = 1.0f;
    float Rc = 0.0f;
    float savedV = 1.0f, savedC = 0.0f;

    // chunk c needs producer groups tg <= 32c+31
    if (wave > 0) { wait2(fb, 31, lane); CONVC(0); }
    __syncthreads();

    for (int c = 0; c < 5; ++c) {
        if (wave > 0 && c + 1 <= 4) {
            const int lim = 32 * (c + 1) + 31;
            wait2(fb, lim > NTG_ - 1 ? NTG_ - 1 : lim, lane);
            CONVC(c + 1);
        }
        if (wave == 0) { CHUNK_BODY(c); }
        __syncthreads();
    }

    if (wave == 0) {
        wait2(fb, NTG_ - 1, lane);   // all flags set (instant); acquire for fblank
        const float fblank = BLb[(size_t)dstar * U1_ + tl];
        const int sl = tlpos ? (tl - 1) : 0;
        float sv = __int_as_float(
            __builtin_amdgcn_readlane(__float_as_int(savedV), sl));
        float sc = __int_as_float(
            __builtin_amdgcn_readlane(__float_as_int(savedC), 0));
        if (lane == 0) {
            const float term = sc + log2f(sv) + fblank;
            if (b == 0) {
                float sum = term;
                for (int l = 1; l < B_; ++l) {
                    while (__hip_atomic_load(&pflag[l], __ATOMIC_ACQUIRE,
                                             __HIP_MEMORY_SCOPE_AGENT) != MAGIC_)
                        __builtin_amdgcn_s_sleep(8);
                    sum += partial[l];
                }
                out[0] = -sum * (LN2_ / B_);
            } else {
                partial[b] = term;
                __threadfence();
                __hip_atomic_store(&pflag[b], MAGIC_,
                                   __ATOMIC_RELEASE, __HIP_MEMORY_SCOPE_AGENT);
            }
        }
    }
}

extern "C" void kernel_launch(void* const* d_in, const int* in_sizes, int n_in,
                              void* d_out, int out_size, void* d_ws, size_t ws_size,
                              hipStream_t stream)
{
    const float* enc     = (const float*)d_in[0];
    const float* dec     = (const float*)d_in[1];
    const int*   targets = (const int*)d_in[2];
    const int*   il      = (const int*)d_in[3];
    const int*   tl      = (const int*)d_in[4];
    float*       out     = (float*)d_out;

    float* BLD     = (float*)d_ws;                              // B*NDIAGP*U1
    float* EMD     = BLD + (size_t)B_ * NDIAGP_ * U1_;          // B*NDIAGP*U_
    int*   flags   = (int*)(EMD + (size_t)B_ * NDIAGP_ * U_);   // B*NTG_
    float* partial = (float*)(flags + B_ * NTG_);               // B_ floats
    int*   pflag   = (int*)(partial + B_);                      // B_ ints

    k_fused<<<NPROD_ + B_, 256, 0, stream>>>(enc, dec, targets, il, tl,
                                             BLD, EMD, flags, partial, pflag, out);
}

// Round 24
// 38.490 us; speedup vs baseline: 3.1553x; 3.1467x over previous
//
#include <hip/hip_runtime.h>

#define B_ 8
#define T_ 256
#define U_ 64
#define U1_ 65
#define V_ 512
#define NDIAGP_ 336   // padded diagonal count (GLDS over-read stays in-bounds)
#define NT_ 2         // t-rows per k_logprobs block
#define CH_ 64        // diagonals per k_alpha chunk

#define LOG2E_ 1.4426950408889634f
#define LN2_   0.6931471805599453f

#if __has_builtin(__builtin_amdgcn_exp2f)
#define EXP2(x) __builtin_amdgcn_exp2f(x)
#else
#define EXP2(x) exp2f(x)
#endif

// ---------------------------------------------------------------------------
// DPP wave-sum: canonical GCN sequence; total lands in lane 63.
// ---------------------------------------------------------------------------
template <int CTRL, int RM>
__device__ __forceinline__ float dppadd(float x) {
    return x + __int_as_float(__builtin_amdgcn_update_dpp(
        0, __float_as_int(x), CTRL, RM, 0xf, true));
}
__device__ __forceinline__ float wave_sum64(float x) {
    x = dppadd<0x111, 0xf>(x);  // row_shr:1
    x = dppadd<0x112, 0xf>(x);  // row_shr:2
    x = dppadd<0x114, 0xf>(x);  // row_shr:4
    x = dppadd<0x118, 0xf>(x);  // row_shr:8
    x = dppadd<0x142, 0xa>(x);  // row_bcast:15 -> rows 1,3
    x = dppadd<0x143, 0xc>(x);  // row_bcast:31 -> rows 2,3
    return x;                    // lane 63 holds the full sum
}

// ---------------------------------------------------------------------------
// Kernel 1: block = (b, pair of t's). Computes exp(dec) INLINE.
// lse2[u] = log2( Σ_v exp(enc_v) * exp(dec_v) ). Diagonal-major log2 outputs:
//   BLD[b][t+u][u]  (stride 65) = (enc[0]+dec[u][0])*log2e     - lse2
//   EMD[b][t+u][u]  (stride 64) = (enc[tgt]+dec[u][tgt])*log2e - lse2
// Block 0 zeroes the output scalar (stream-ordered before k_alpha).
// ---------------------------------------------------------------------------
__global__ __launch_bounds__(256) void k_logprobs(
    const float* __restrict__ enc, const float* __restrict__ dec,
    const int* __restrict__ targets,
    float* __restrict__ BLD, float* __restrict__ EMD,
    float* __restrict__ out)
{
    const int blk  = blockIdx.x;           // 0 .. 1023
    const int b    = blk % B_;             // XCD affinity with k_alpha
    const int tg   = blk / B_;
    const int t0   = tg * NT_;
    const int wave = threadIdx.x >> 6;
    const int lane = threadIdx.x & 63;

    if (blk == 0 && threadIdx.x == 0) out[0] = 0.0f;

    float4 xe0[NT_], xe1[NT_];
    float  er0[NT_];
    #pragma unroll
    for (int j = 0; j < NT_; ++j) {
        const float* erow = enc + (size_t)(b * T_ + t0 + j) * V_;
        float4 e0 = *(const float4*)(erow + lane * 4);
        float4 e1 = *(const float4*)(erow + 256 + lane * 4);
        xe0[j].x = __expf(e0.x); xe0[j].y = __expf(e0.y);
        xe0[j].z = __expf(e0.z); xe0[j].w = __expf(e0.w);
        xe1[j].x = __expf(e1.x); xe1[j].y = __expf(e1.y);
        xe1[j].z = __expf(e1.z); xe1[j].w = __expf(e1.w);
        er0[j] = erow[0];
    }

    for (int u = wave; u <= U_; u += 4) {
        const float* drow = dec + (size_t)(b * U1_ + u) * V_;
        float4 d0 = *(const float4*)(drow + lane * 4);
        float4 d1 = *(const float4*)(drow + 256 + lane * 4);
        d0.x = __expf(d0.x); d0.y = __expf(d0.y);
        d0.z = __expf(d0.z); d0.w = __expf(d0.w);
        d1.x = __expf(d1.x); d1.y = __expf(d1.y);
        d1.z = __expf(d1.z); d1.w = __expf(d1.w);

        float s[NT_];
        #pragma unroll
        for (int j = 0; j < NT_; ++j) {
            float sA = xe0[j].x * d0.x;
            float sB = xe1[j].x * d1.x;
            sA = fmaf(xe0[j].y, d0.y, sA);  sB = fmaf(xe1[j].y, d1.y, sB);
            sA = fmaf(xe0[j].z, d0.z, sA);  sB = fmaf(xe1[j].z, d1.z, sB);
            sA = fmaf(xe0[j].w, d0.w, sA);  sB = fmaf(xe1[j].w, d1.w, sB);
            s[j] = sA + sB;
        }

        #pragma unroll
        for (int j = 0; j < NT_; ++j)
            s[j] = wave_sum64(s[j]);

        if (lane == 63) {
            const float d_blank = drow[0];
            int   tgt = 0;
            float d_tgt = 0.0f;
            if (u < U_) { tgt = targets[b * U_ + u]; d_tgt = drow[tgt]; }
            #pragma unroll
            for (int j = 0; j < NT_; ++j) {
                const int t  = t0 + j;
                const int dg = t + u;
                const float lse2 = log2f(s[j]);
                BLD[((size_t)b * NDIAGP_ + dg) * U1_ + u] =
                    (er0[j] + d_blank) * LOG2E_ - lse2;
                if (u < U_) {
                    const float* er = enc + (size_t)(b * T_ + t) * V_;
                    EMD[((size_t)b * NDIAGP_ + dg) * U_ + u] =
                        (er[tgt] + d_tgt) * LOG2E_ - lse2;
                }
            }
        }
    }
}

// ---------------------------------------------------------------------------
// Kernel 2: alpha recursion. 8 waves: wave 0 consumes; waves 1-7 produce
// (GLDS raw c+2, CONV c+1 packed float4 pairs). Linear domain vs. log2
// reference R; renorm every 8 diagonals (exact power-of-2); branchless
// answer capture; one atomicAdd at kernel end.
// ---------------------------------------------------------------------------
__device__ __forceinline__ float wshr1(float x) {
    return __int_as_float(__builtin_amdgcn_update_dpp(
        0, __float_as_int(x), 0x138, 0xf, 0xf, true));
}
template <int CTRL>
__device__ __forceinline__ float dppmax(float x) {
    return fmaxf(x, __int_as_float(__builtin_amdgcn_update_dpp(
        0, __float_as_int(x), CTRL, 0xf, 0xf, false)));
}
__device__ __forceinline__ float wave_max64(float x) {
    x = dppmax<0x111>(x);  // row_shr:1
    x = dppmax<0x112>(x);  // row_shr:2
    x = dppmax<0x114>(x);  // row_shr:4
    x = dppmax<0x118>(x);  // row_shr:8
    x = dppmax<0x142>(x);  // row_bcast:15
    x = dppmax<0x143>(x);  // row_bcast:31
    return __int_as_float(__builtin_amdgcn_readlane(__float_as_int(x), 63));
}

#define GLDS(c_) do {                                                           \
    if (wave > 0) {                                                             \
        const float* gbl = BLb + (size_t)(c_) * CH_ * U1_;                      \
        const float* gem = EMb + (size_t)(c_) * CH_ * U_;                       \
        float* lbl_ = sRBL[(c_) & 1];                                           \
        float* lem_ = sREM[(c_) & 1];                                           \
        for (int i = wave - 1; i < 17; i += 7)                                  \
            __builtin_amdgcn_global_load_lds(                                   \
                (const __attribute__((address_space(1))) void*)(gbl + i * 256 + lane * 4), \
                (__attribute__((address_space(3))) void*)(lbl_ + i * 256), 16, 0, 0);      \
        for (int i = wave - 1; i < 16; i += 7)                                  \
            __builtin_amdgcn_global_load_lds(                                   \
                (const __attribute__((address_space(1))) void*)(gem + i * 256 + lane * 4), \
                (__attribute__((address_space(3))) void*)(lem_ + i * 256), 16, 0, 0);      \
    }                                                                           \
} while (0)

#define CONV(c_) do {                                                           \
    if (wave > 0) {                                                             \
        const float* rbl = sRBL[(c_) & 1];                                      \
        const float* rem = sREM[(c_) & 1];                                      \
        float4* pv_ = sPV[(c_) & 1];                                            \
        float*  pc_ = sPC[(c_) & 1];                                            \
        _Pragma("unroll 3")                                                     \
        for (int i = wave - 1; i < CH_; i += 7) {                               \
            const float bl = rbl[i * U1_ + lane + 1];                           \
            const float em = rem[i * U_ + lane];                                \
            const float pc = ((c_) == 4) ? rbl[i * U1_ + i + 1]                 \
                                         : rbl[i * U1_];                        \
            float vb = fminf(bl - pc, 126.0f);                                  \
            float ve = fminf(em - pc, 126.0f);                                  \
            if ((c_) == 0 && lane == i) vb = -200.0f;                           \
            if ((c_) == 4 && lane <= i) { vb = -200.0f; ve = -200.0f; }         \
            ((float2*)&pv_[(i >> 1) * 64 + lane])[i & 1] =                      \
                make_float2(EXP2(vb), EXP2(ve));                                \
            if (lane == 0) pc_[i] = pc;                                         \
        }                                                                       \
    }                                                                           \
} while (0)

#define LOADG(PV, PCQ, g_) do {                                                 \
    _Pragma("unroll")                                                           \
    for (int k = 0; k < 4; ++k)                                                 \
        PV[k] = pvb[(4 * (g_) + k) * 64 + lane];                                \
    PCQ[0] = pcb4[2 * (g_)];                                                    \
    PCQ[1] = pcb4[2 * (g_) + 1];                                                \
} while (0)

#define PCSEL(PCQ, j_) ((j_) < 4 ? ((j_) == 0 ? PCQ[0].x : (j_) == 1 ? PCQ[0].y \
                                  : (j_) == 2 ? PCQ[0].z : PCQ[0].w)            \
                                 : ((j_) == 4 ? PCQ[1].x : (j_) == 5 ? PCQ[1].y \
                                  : (j_) == 6 ? PCQ[1].z : PCQ[1].w))

#define COMPG(PV, PCQ, g_) do {                                                 \
    _Pragma("unroll")                                                           \
    for (int j = 0; j < 8; ++j) {                                               \
        const int d = d0 + 8 * (g_) + j + 1;                                    \
        const float pbv = (j & 1) ? PV[j >> 1].z : PV[j >> 1].x;                \
        const float pev = (j & 1) ? PV[j >> 1].w : PV[j >> 1].y;                \
        const float pcj = PCSEL(PCQ, j);                                        \
        float sr = wshr1(r);                                                    \
        sr = lane0 ? r0 : sr;                                                   \
        r = fmaf(sr, pev, r * pbv);                                             \
        const bool cap = (d == cap_d);                                          \
        savedV = cap ? (tlpos ? r : r0) : savedV;                               \
        savedC = cap ? (tlpos ? Rc + pcj : Rc) : savedC;                        \
        Rc += pcj;                                                              \
    }                                                                           \
    {                                                                           \
        float m = wave_max64(r);                                                \
        int mb = __float_as_int(m);                                             \
        int e = (mb >> 23) - 127;                                               \
        e = (mb >= 0x00800000) ? e : 0;                                         \
        float sc = __int_as_float((127 - e) << 23);                             \
        r *= sc;  r0 *= sc;  Rc += (float)e;                                    \
    }                                                                           \
} while (0)

#define CHUNK_BODY(c_) do {                                                     \
    const float4* pvb  = sPV[(c_) & 1];                                         \
    const float4* pcb4 = (const float4*)sPC[(c_) & 1];                          \
    const int d0 = CH_ * (c_);                                                  \
    float4 pvA[4], pvB[4];                                                      \
    float4 pcA[2], pcB[2];                                                      \
    LOADG(pvA, pcA, 0);                                                         \
    for (int g = 0; g < 8; g += 2) {                                            \
        LOADG(pvB, pcB, g + 1);                                                 \
        COMPG(pvA, pcA, g);                                                     \
        if (g + 2 < 8) LOADG(pvA, pcA, g + 2);                                  \
        COMPG(pvB, pcB, g + 1);                                                 \
    }                                                                           \
} while (0)

__global__ __launch_bounds__(512) void k_alpha(
    const float* __restrict__ BLD, const float* __restrict__ EMD,
    const int* __restrict__ il_, const int* __restrict__ tl_,
    float* __restrict__ sink)
{
    __shared__ __align__(16) float  sRBL[2][17 * 256];   // raw BL (34 KB)
    __shared__ __align__(16) float  sREM[2][16 * 256];   // raw EM (32 KB)
    __shared__ __align__(16) float4 sPV[2][32 * 64];     // packed pairs (64 KB)
    __shared__ __align__(16) float  sPC[2][CH_];         // refs (512 B)

    const int b    = blockIdx.x;
    const int wave = threadIdx.x >> 6;
    const int lane = threadIdx.x & 63;
    const int il   = il_[b];
    const int tl   = tl_[b];
    const int dstar = il - 1 + tl;
    const float* BLb = BLD + (size_t)b * NDIAGP_ * U1_;
    const float* EMb = EMD + (size_t)b * NDIAGP_ * U_;
    const float fblank = BLb[(size_t)dstar * U1_ + tl];

    const bool lane0 = (lane == 0);
    const bool tlpos = (tl > 0);
    const int  cap_d = tlpos ? dstar : il;

    float r  = 0.0f;
    float r0 = 1.0f;
    float Rc = 0.0f;
    float savedV = 1.0f, savedC = 0.0f;

    GLDS(0);
    __syncthreads();
    GLDS(1);
    CONV(0);
    __syncthreads();

    for (int c = 0; c < 5; ++c) {
        if (c + 2 <= 4) GLDS(c + 2);
        if (c + 1 <= 4) CONV(c + 1);
        if (wave == 0) { CHUNK_BODY(c); }
        __syncthreads();
    }

    if (wave == 0) {
        const int sl = tlpos ? (tl - 1) : 0;
        float sv = __int_as_float(
            __builtin_amdgcn_readlane(__float_as_int(savedV), sl));
        float sc = __int_as_float(
            __builtin_amdgcn_readlane(__float_as_int(savedC), 0));
        if (lane == 0)
            atomicAdd(sink, -(sc + log2f(sv) + fblank) * (LN2_ / B_));
    }
}

extern "C" void kernel_launch(void* const* d_in, const int* in_sizes, int n_in,
                              void* d_out, int out_size, void* d_ws, size_t ws_size,
                              hipStream_t stream)
{
    const float* enc     = (const float*)d_in[0];
    const float* dec     = (const float*)d_in[1];
    const int*   targets = (const int*)d_in[2];
    const int*   il      = (const int*)d_in[3];
    const int*   tl      = (const int*)d_in[4];
    float*       out     = (float*)d_out;

    float* BLD = (float*)d_ws;                            // B*NDIAGP*U1
    float* EMD = BLD + (size_t)B_ * NDIAGP_ * U1_;        // B*NDIAGP*U_

    k_logprobs<<<B_ * T_ / NT_, 256, 0, stream>>>(enc, dec, targets, BLD, EMD, out);
    k_alpha<<<B_, 512, 0, stream>>>(BLD, EMD, il, tl, out);
}